// Round 3
// baseline (949.296 us; speedup 1.0000x reference)
//
#include <hip/hip_runtime.h>

// Problem constants (match reference setup_inputs)
constexpr int T = 8;
constexpr int R = 200000;
constexpr int D = 128;
constexpr int B = 2048;
constexpr int NUM_BAGS = T * B;  // 16384
constexpr int N_TOTAL = 524288;  // T * B * L

typedef int   iv4 __attribute__((ext_vector_type(4)));
typedef float fv2 __attribute__((ext_vector_type(2)));

// ROUND-3 PROBE KERNEL. Functionally identical to the round-0 kernel, but
// the full gather+accumulate phase is executed TWICE. The second pass:
//   - perturbs every address by a runtime zero (zoff) so its loads cannot
//     be CSE'd/DCE'd against the first pass,
//   - accumulates into separate registers folded in with weight
//     (float)zoff == 0.0f, so the output is bit-identical.
// Purpose: dur_us(round3) - dur_us(round2) == cost of one full gather
// phase inside the timed window, resolving how much of the ~930us window
// the kernel's gather actually owns (vs fixed harness fills/restores).
__global__ __launch_bounds__(256)
void qembag_kernel(const int* __restrict__ indices,
                   const int* __restrict__ offsets,
                   const int* __restrict__ qweights,
                   const float* __restrict__ scale_shift,
                   float* __restrict__ out) {
    const int wave_id = (int)((blockIdx.x * blockDim.x + threadIdx.x) >> 6);
    if (wave_id >= NUM_BAGS) return;
    const int lane = (int)(threadIdx.x & 63);
    const int half = lane >> 5;   // which lookup of an interleaved pair
    const int sub  = lane & 31;   // 16B chunk within the 512B row

    const int t     = wave_id >> 11;      // bag / B   (B = 2048)
    const int batch = wave_id & (B - 1);  // bag % B

    // Runtime zero the compiler cannot fold: offsets[NUM_BAGS] == N_TOTAL
    // by construction (CSR terminator), but that is data, not a constant.
    const int zoff = (offsets[NUM_BAGS] == N_TOTAL) ? 0 : 1;

    const int start = offsets[wave_id];
    const int end   = offsets[wave_id + 1];
    const int len   = end - start;
    const int C     = len >> 4;           // full chunks of 16 lookups

    const long tbase = (long)t * R;
    const iv4* qw4 = (const iv4*)qweights;    // row r -> qw4[r*32 + sub]
    const fv2* ss2 = (const fv2*)scale_shift; // row r -> ss2[r]

    float acc0 = 0.f, acc1 = 0.f, acc2 = 0.f, acc3 = 0.f;
    float sshift = 0.f;

    // ---------------- PASS 1 (real) ----------------
    {
        int idxb[8];
        if (C > 0) {
#pragma unroll
            for (int k = 0; k < 8; ++k) idxb[k] = indices[start + half + 2 * k];
        }
        for (int c = 0; c < C; ++c) {
            iv4 q[8];
            fv2 s[8];
#pragma unroll
            for (int k = 0; k < 8; ++k) {
                const long r = tbase + idxb[k];
                q[k] = qw4[r * 32 + sub];
                s[k] = ss2[r];
            }
            if (c + 1 < C) {
                const int nbase = start + ((c + 1) << 4) + half;
#pragma unroll
                for (int k = 0; k < 8; ++k) idxb[k] = indices[nbase + 2 * k];
            }
#pragma unroll
            for (int k = 0; k < 8; ++k) {
                const float sc = s[k].x;
                sshift += s[k].y;
                acc0 = fmaf((float)q[k].x, sc, acc0);
                acc1 = fmaf((float)q[k].y, sc, acc1);
                acc2 = fmaf((float)q[k].z, sc, acc2);
                acc3 = fmaf((float)q[k].w, sc, acc3);
            }
        }
        for (int j = start + (C << 4) + half; j < end; j += 2) {
            const long r = tbase + indices[j];
            const iv4 q = qw4[r * 32 + sub];
            const fv2 ss = ss2[r];
            sshift += ss.y;
            acc0 = fmaf((float)q.x, ss.x, acc0);
            acc1 = fmaf((float)q.y, ss.x, acc1);
            acc2 = fmaf((float)q.z, ss.x, acc2);
            acc3 = fmaf((float)q.w, ss.x, acc3);
        }
    }

    // ---------------- PASS 2 (probe duplicate, runtime-dead) ----------------
    float b0 = 0.f, b1 = 0.f, b2 = 0.f, b3 = 0.f, bsh = 0.f;
    {
        int idxb[8];
        if (C > 0) {
#pragma unroll
            for (int k = 0; k < 8; ++k)
                idxb[k] = indices[start + half + 2 * k + zoff];  // zoff==0
        }
        for (int c = 0; c < C; ++c) {
            iv4 q[8];
            fv2 s[8];
#pragma unroll
            for (int k = 0; k < 8; ++k) {
                const long r = tbase + idxb[k] + zoff;           // zoff==0
                q[k] = qw4[r * 32 + sub + zoff];                 // distinct expr
                s[k] = ss2[r + zoff];
            }
            if (c + 1 < C) {
                const int nbase = start + ((c + 1) << 4) + half;
#pragma unroll
                for (int k = 0; k < 8; ++k)
                    idxb[k] = indices[nbase + 2 * k + zoff];
            }
#pragma unroll
            for (int k = 0; k < 8; ++k) {
                const float sc = s[k].x;
                bsh += s[k].y;
                b0 = fmaf((float)q[k].x, sc, b0);
                b1 = fmaf((float)q[k].y, sc, b1);
                b2 = fmaf((float)q[k].z, sc, b2);
                b3 = fmaf((float)q[k].w, sc, b3);
            }
        }
        for (int j = start + (C << 4) + half; j < end; j += 2) {
            const long r = tbase + indices[j + zoff] + zoff;
            const iv4 q = qw4[r * 32 + sub + zoff];
            const fv2 ss = ss2[r + zoff];
            bsh += ss.y;
            b0 = fmaf((float)q.x, ss.x, b0);
            b1 = fmaf((float)q.y, ss.x, b1);
            b2 = fmaf((float)q.z, ss.x, b2);
            b3 = fmaf((float)q.w, ss.x, b3);
        }
    }

    // Fold probe pass with runtime weight 0.0f: output is bit-identical.
    const float zf = (float)zoff;   // 0.0f at runtime
    acc0 = fmaf(zf, b0, acc0);
    acc1 = fmaf(zf, b1, acc1);
    acc2 = fmaf(zf, b2, acc2);
    acc3 = fmaf(zf, b3, acc3);
    sshift = fmaf(zf, bsh, sshift);

    acc0 += sshift; acc1 += sshift; acc2 += sshift; acc3 += sshift;

    // Fold the two half-wave partial sums: lane s += lane s+32
    acc0 += __shfl_down(acc0, 32);
    acc1 += __shfl_down(acc1, 32);
    acc2 += __shfl_down(acc2, 32);
    acc3 += __shfl_down(acc3, 32);

    if (half == 0) {
        float4 v = make_float4(acc0, acc1, acc2, acc3);
        ((float4*)(out + (long)batch * (T * D) + t * D))[sub] = v;
    }
}

extern "C" void kernel_launch(void* const* d_in, const int* in_sizes, int n_in,
                              void* d_out, int out_size, void* d_ws, size_t ws_size,
                              hipStream_t stream) {
    const int*   indices     = (const int*)d_in[0];
    const int*   offsets     = (const int*)d_in[1];
    const int*   qweights    = (const int*)d_in[2];
    const float* scale_shift = (const float*)d_in[3];
    float*       out         = (float*)d_out;

    const int blocks = NUM_BAGS / 4;  // 4 waves/block, one wave per bag
    qembag_kernel<<<blocks, 256, 0, stream>>>(indices, offsets, qweights,
                                              scale_shift, out);
}